// Round 4
// baseline (135.812 us; speedup 1.0000x reference)
//
#include <hip/hip_runtime.h>
#include <math.h>

#define BB 1024
#define LL 256
#define VV 50000
#define EE 300
#define AA 30
#define WORD_THRES 0.2f
#define COS_EPS_F 1e-8f
#define NEG_INF_F -1e9f
#define RECHECK_DELTA 2e-4f

typedef __attribute__((ext_vector_type(8))) short bf16x8;
typedef __attribute__((ext_vector_type(4))) float f32x4;

#define MFMA16(a, b, c) __builtin_amdgcn_mfma_f32_16x16x32_bf16((a), (b), (c), 0, 0, 0)

// async global -> LDS DMA, 16 B per lane. LDS dest = wave-uniform base +
// lane*16 (per-thread linear pointers reconstruct exactly); global src is
// per-lane. No VGPR destination -> all staging loads stay in flight.
__device__ __forceinline__ void gld_lds16(const float* g, float* l) {
    typedef const __attribute__((address_space(1))) void* gas_p;
    typedef __attribute__((address_space(3))) void* las_p;
    __builtin_amdgcn_global_load_lds((gas_p)g, (las_p)l, 16, 0, 0);
}

// fp32 -> bf16 truncation split: x = hi + lo with |x - hi - lo| <~ 2^-17 |x|.
__device__ __forceinline__ unsigned pack_hi(float a, float b) {
    return (__float_as_uint(a) >> 16) | (__float_as_uint(b) & 0xFFFF0000u);
}
__device__ __forceinline__ float hi_part(float a) {
    return __uint_as_float(__float_as_uint(a) & 0xFFFF0000u);
}
__device__ __forceinline__ void cvt_hilo(const float4 f0, const float4 f1,
                                         uint4& uh, uint4& ul) {
    uh.x = pack_hi(f0.x, f0.y);
    uh.y = pack_hi(f0.z, f0.w);
    uh.z = pack_hi(f1.x, f1.y);
    uh.w = pack_hi(f1.z, f1.w);
    const float l0 = f0.x - hi_part(f0.x), l1 = f0.y - hi_part(f0.y);
    const float l2 = f0.z - hi_part(f0.z), l3 = f0.w - hi_part(f0.w);
    const float l4 = f1.x - hi_part(f1.x), l5 = f1.y - hi_part(f1.y);
    const float l6 = f1.z - hi_part(f1.z), l7 = f1.w - hi_part(f1.w);
    ul.x = pack_hi(l0, l1);
    ul.y = pack_hi(l2, l3);
    ul.z = pack_hi(l4, l5);
    ul.w = pack_hi(l6, l7);
}

// ---------------------------------------------------------------------------
// Kernel 1 (MFMA + DMA staging):
// cent[v] = max_a ((cos(a_emb[a], w_emb[v]) > thres ? cos : 0) * w[a])
// 128 threads / 32 vocab rows per block, grid 1563. The block's A-tile is one
// contiguous 38400 B span of w_emb -> staged via 19 global_load_lds dwordx4
// per thread (1 KB contiguous per wave-instruction, no VGPR destinations, all
// in flight). Previous rounds' reg-based loads were capped at ~2-3 outstanding
// scattered loads/wave (VGPR=68 proved the ring collapsed) -> 43 us invariant.
// LDS 79.6 KB -> 2 blocks/CU: one block's DMA overlaps the other's compute.
// Compute: wave = 16-row M-tile, N=30 as two 16-col tiles, K 300->320,
// hi/lo bf16 split (6 MFMAs/step, ~1e-5 rel. accuracy). Near-threshold cos
// (|cos-0.2| < 2e-4, ~10 globally) re-checked in exact fp32 from the LDS copy.
// ---------------------------------------------------------------------------
__global__ void __launch_bounds__(128) cent_kernel(
    const float* __restrict__ w_emb,     // [V, E]
    const float* __restrict__ a_emb,     // [A, E]
    const float* __restrict__ a_weight,  // [A]
    float* __restrict__ cent)            // [V]
{
    __shared__ float4 s_a4[2400];        // 32 rows x 300 f = 38400 B (A-tile)
    __shared__ uint4 s_bfrag[40 * 64];   // [ks*4 + tt*2 + hi/lo][lane], 40960 B
    __shared__ float s_scale[32];
    __shared__ float s_aw[32];

    const int t = threadIdx.x;
    const int l = t & 63;
    const int w = t >> 6;
    const int m = l & 15;        // row within wave tile / aspect lane id
    const int kg = l >> 4;       // k-chunk selector (8 elements each)
    float* s_af = (float*)s_a4;

    // ---- 1) issue A-tile DMA: contiguous 38400 B, 19 instrs/thread ----
    {
        const float* gbase = w_emb + (size_t)blockIdx.x * 32 * EE;
        const float* gend = w_emb + (size_t)VV * EE;   // last block clamp
#pragma unroll
        for (int i = 0; i < 19; ++i) {
            if (i < 18 || t < 96) {                    // 38400/2048 = 18.75
                const int off = i * 512 + t * 4;       // floats
                const float* src = gbase + off;
                if (src > gend - 4) src = gend - 4;    // stays 16B-aligned
                gld_lds16(src, s_af + off);
            }
        }
    }

    // ---- 2) aspect inv-norms + weights (4 lanes/aspect, threads 0..119) ----
    {
        const int a = t >> 2, j = t & 3;
        if (a < AA) {
            const float4* a4 = (const float4*)a_emb + a * 75;
            float n2a = 0.f;
            for (int c = j; c < 75; c += 4) {
                const float4 x = a4[c];
                n2a += x.x * x.x + x.y * x.y + x.z * x.z + x.w * x.w;
            }
            n2a += __shfl_xor(n2a, 1);
            n2a += __shfl_xor(n2a, 2);
            if (j == 0) {
                s_scale[a] = 1.f / fmaxf(sqrtf(n2a), COS_EPS_F);
                s_aw[a] = a_weight[a];
            }
        }
        if (t == 30 || t == 31) { s_scale[t] = 0.f; s_aw[t] = 0.f; }  // pads
    }

    // ---- 3) build B fragments (a_emb hi/lo), waves split the 10 k-steps ----
    for (int ks = w; ks < 10; ks += 2) {
        const int kb = kg * 8 + 32 * ks;
#pragma unroll
        for (int tt = 0; tt < 2; ++tt) {
            const int col = tt * 16 + m;         // aspect index (pad >= 30)
            float4 f0 = {0.f, 0.f, 0.f, 0.f}, f1 = {0.f, 0.f, 0.f, 0.f};
            if (col < AA) {
                const float* ap = a_emb + col * EE;
                if (kb <= 296) f0 = *(const float4*)(ap + kb);
                if (kb <= 292) f1 = *(const float4*)(ap + kb + 4);
            }
            uint4 uh, ul;
            cvt_hilo(f0, f1, uh, ul);
            s_bfrag[(ks * 4 + tt * 2 + 0) * 64 + l] = uh;
            s_bfrag[(ks * 4 + tt * 2 + 1) * 64 + l] = ul;
        }
    }

    // ---- 4) drain DMA + barrier ----
    asm volatile("s_waitcnt vmcnt(0)" ::: "memory");
    __syncthreads();

    // ---- 5) compute: one 16-row M-tile per wave, A sourced from LDS ----
    const int vtile = blockIdx.x * 32 + w * 16;
    const float* __restrict__ arow = s_af + (w * 16 + m) * EE;

    f32x4 acc0 = {0.f, 0.f, 0.f, 0.f};
    f32x4 acc1 = {0.f, 0.f, 0.f, 0.f};
    float n2 = 0.f;
    const uint4* __restrict__ bp0 = s_bfrag + l;

#pragma unroll
    for (int i = 0; i < 10; ++i) {
        const int kb = kg * 8 + 32 * i;
        float4 f0 = *(const float4*)(arow + kb);       // ds_read_b128
        float4 f1 = *(const float4*)(arow + kb + 4);   // (tail overreads land
        if (i == 9) {                                  //  in-LDS, zeroed here)
            const float4 z = {0.f, 0.f, 0.f, 0.f};
            if (kg >= 2) f0 = z;                       // k >= 304
            if (kg >= 1) f1 = z;                       // k >= 300
        }
        n2 = fmaf(f0.x, f0.x, fmaf(f0.y, f0.y, fmaf(f0.z, f0.z, fmaf(f0.w, f0.w, n2))));
        n2 = fmaf(f1.x, f1.x, fmaf(f1.y, f1.y, fmaf(f1.z, f1.z, fmaf(f1.w, f1.w, n2))));
        uint4 uh, ul;
        cvt_hilo(f0, f1, uh, ul);
        const bf16x8 ah = __builtin_bit_cast(bf16x8, uh);
        const bf16x8 al = __builtin_bit_cast(bf16x8, ul);
        const uint4* bp = bp0 + i * 256;
        const bf16x8 bh0 = __builtin_bit_cast(bf16x8, bp[0]);
        const bf16x8 bl0 = __builtin_bit_cast(bf16x8, bp[64]);
        const bf16x8 bh1 = __builtin_bit_cast(bf16x8, bp[128]);
        const bf16x8 bl1 = __builtin_bit_cast(bf16x8, bp[192]);
        acc0 = MFMA16(ah, bh0, acc0);
        acc1 = MFMA16(ah, bh1, acc1);
        acc0 = MFMA16(ah, bl0, acc0);
        acc1 = MFMA16(ah, bl1, acc1);
        acc0 = MFMA16(al, bh0, acc0);
        acc1 = MFMA16(al, bh1, acc1);
    }

    // ---- 6) epilogue ----
    n2 += __shfl_xor(n2, 16);
    n2 += __shfl_xor(n2, 32);
    // C/D layout: lane l holds D[rows kg*4+j][col m (+16 for acc1)]

    const float sc0 = s_scale[m], aw0 = s_aw[m];
    const float sc1 = s_scale[16 + m], aw1 = s_aw[16 + m];
    const bool col1ok = (16 + m) < AA;
    float mx[4];
#pragma unroll
    for (int j = 0; j < 4; ++j) {
        const int r = kg * 4 + j;                 // row within wave tile
        const float n2r = __int_as_float(
            __builtin_amdgcn_ds_bpermute(r << 2, __float_as_int(n2)));
        const float inv_x = 1.f / fmaxf(sqrtf(n2r), COS_EPS_F);
        float c0 = acc0[j] * sc0 * inv_x;
        float c1 = acc1[j] * sc1 * inv_x;
        // exact fp32 recheck for near-threshold cos (reads the LDS row copy)
        if (fabsf(c0 - WORD_THRES) < RECHECK_DELTA) {
            const float* wr = s_af + (w * 16 + r) * EE;
            const float* ar = a_emb + m * EE;
            float d = 0.f;
            for (int k = 0; k < EE; ++k) d = fmaf(wr[k], ar[k], d);
            c0 = d * sc0 * inv_x;
        }
        if (col1ok && fabsf(c1 - WORD_THRES) < RECHECK_DELTA) {
            const float* wr = s_af + (w * 16 + r) * EE;
            const float* ar = a_emb + (16 + m) * EE;
            float d = 0.f;
            for (int k = 0; k < EE; ++k) d = fmaf(wr[k], ar[k], d);
            c1 = d * sc1 * inv_x;
        }
        float mj = fmaxf((c0 > WORD_THRES) ? c0 * aw0 : 0.f,
                         (c1 > WORD_THRES) ? c1 * aw1 : 0.f);
        mj = fmaxf(mj, __shfl_xor(mj, 1));
        mj = fmaxf(mj, __shfl_xor(mj, 2));
        mj = fmaxf(mj, __shfl_xor(mj, 4));
        mj = fmaxf(mj, __shfl_xor(mj, 8));
        mx[j] = mj;
    }
    if (m == 0 && vtile < VV) {                   // 50000 = 3125 full tiles
        const float4 o = {mx[0], mx[1], mx[2], mx[3]};
        *(float4*)(cent + vtile + kg * 4) = o;
    }
}

// ---------------------------------------------------------------------------
// Kernel 2: ONE WAVE per batch row (4 rows/block, 256 blocks). Lane owns 4
// contiguous positions -> int4 input load, 4 cent gathers, all reductions as
// one 6-level shuffle butterfly, coalesced float4 attention write. One barrier.
// Sparse z over the ~2 active positions per row.
// ---------------------------------------------------------------------------
__global__ void __launch_bounds__(256) row_kernel(
    const int* __restrict__ inputs,   // [B, L]
    const float* __restrict__ w_emb,  // [V, E]
    const float* __restrict__ cent,   // [V]
    float* __restrict__ out)          // enc_out [B,E] | a [B,L] | cs [B]
{
    const int w = threadIdx.x >> 6;
    const int lane = threadIdx.x & 63;
    const int b = blockIdx.x * 4 + w;           // wave-per-row

    __shared__ int s_id[4][LL];
    __shared__ float s_w[4][LL];
    __shared__ int s_n[4];

    if (lane == 0) s_n[w] = 0;

    const int4 id4 = *(const int4*)(inputs + b * LL + lane * 4);
    const float c0 = cent[id4.x];
    const float c1 = cent[id4.y];
    const float c2 = cent[id4.z];
    const float c3 = cent[id4.w];
    const float sc0 = (c0 > 0.f) ? c0 : NEG_INF_F;
    const float sc1 = (c1 > 0.f) ? c1 : NEG_INF_F;
    const float sc2 = (c2 > 0.f) ? c2 : NEG_INF_F;
    const float sc3 = (c3 > 0.f) ? c3 : NEG_INF_F;

    float s1 = c0 + c1 + c2 + c3;                             // sum cent
    float s2 = (id4.x != 0 ? 1.f : 0.f) + (id4.y != 0 ? 1.f : 0.f) +
               (id4.z != 0 ? 1.f : 0.f) + (id4.w != 0 ? 1.f : 0.f);
    float s3 = fmaxf(fmaxf(sc0, sc1), fmaxf(sc2, sc3));       // max score
#pragma unroll
    for (int o = 1; o < 64; o <<= 1) {
        s1 += __shfl_xor(s1, o);
        s2 += __shfl_xor(s2, o);
        s3 = fmaxf(s3, __shfl_xor(s3, o));
    }
    const float mx = s3;

    const float p0 = expf(sc0 - mx);
    const float p1 = expf(sc1 - mx);
    const float p2 = expf(sc2 - mx);
    const float p3 = expf(sc3 - mx);
    float s4 = p0 + p1 + p2 + p3;
#pragma unroll
    for (int o = 1; o < 64; o <<= 1) s4 += __shfl_xor(s4, o);

    const float rinv = 1.f / s4;
    const float4 av = {p0 * rinv, p1 * rinv, p2 * rinv, p3 * rinv};
    *(float4*)(out + BB * EE + b * LL + lane * 4) = av;       // attention

    const float cs = s1 / (s2 + 1e-5f);
    const float gate = (cs > 1e-4f) ? 1.f : 0.f;
    if (lane == 0) out[BB * EE + BB * LL + b] = cs;

    // per-wave active list (score > -1e8 <=> cent > 0)
    if (sc0 > -1e8f) { const int i = atomicAdd(&s_n[w], 1); s_id[w][i] = id4.x; s_w[w][i] = av.x; }
    if (sc1 > -1e8f) { const int i = atomicAdd(&s_n[w], 1); s_id[w][i] = id4.y; s_w[w][i] = av.y; }
    if (sc2 > -1e8f) { const int i = atomicAdd(&s_n[w], 1); s_id[w][i] = id4.z; s_w[w][i] = av.z; }
    if (sc3 > -1e8f) { const int i = atomicAdd(&s_n[w], 1); s_id[w][i] = id4.w; s_w[w][i] = av.w; }
    __syncthreads();                              // order LDS list vs reads
    const int n = s_n[w];

    // z over active entries; lane owns float4 col lane (+ col 64+lane if <11)
    float4 accA = {0.f, 0.f, 0.f, 0.f};
    float4 accB = {0.f, 0.f, 0.f, 0.f};
    for (int i = 0; i < n; ++i) {
        const float wgt = s_w[w][i];
        const float4* rp = (const float4*)(w_emb + (size_t)s_id[w][i] * EE);
        const float4 ra = rp[lane];
        accA.x += wgt * ra.x; accA.y += wgt * ra.y;
        accA.z += wgt * ra.z; accA.w += wgt * ra.w;
        if (lane < 11) {
            const float4 rb = rp[64 + lane];
            accB.x += wgt * rb.x; accB.y += wgt * rb.y;
            accB.z += wgt * rb.z; accB.w += wgt * rb.w;
        }
    }
    accA.x *= gate; accA.y *= gate; accA.z *= gate; accA.w *= gate;
    *(float4*)(out + b * EE + 4 * lane) = accA;
    if (lane < 11) {
        accB.x *= gate; accB.y *= gate; accB.z *= gate; accB.w *= gate;
        *(float4*)(out + b * EE + 256 + 4 * lane) = accB;
    }
}

// ---------------------------------------------------------------------------
extern "C" void kernel_launch(void* const* d_in, const int* in_sizes, int n_in,
                              void* d_out, int out_size, void* d_ws, size_t ws_size,
                              hipStream_t stream) {
    const int* inputs = (const int*)d_in[0];
    const float* w_emb = (const float*)d_in[1];
    const float* a_emb = (const float*)d_in[2];
    const float* a_weight = (const float*)d_in[3];
    float* out = (float*)d_out;
    float* cent = (float*)d_ws;  // 50000 floats = 200 KB scratch

    cent_kernel<<<(VV + 31) / 32, 128, 0, stream>>>(w_emb, a_emb, a_weight, cent);
    row_kernel<<<BB / 4, 256, 0, stream>>>(inputs, w_emb, cent, out);
}

// Round 5
// 115.356 us; speedup vs baseline: 1.1773x; 1.1773x over previous
//
#include <hip/hip_runtime.h>
#include <math.h>

#define BB 1024
#define LL 256
#define VV 50000
#define EE 300
#define AA 30
#define WORD_THRES 0.2f
#define COS_EPS_F 1e-8f
#define NEG_INF_F -1e9f
#define RECHECK_DELTA 2e-4f
#define CGRID 256
#define NTILES 782            // ceil(50000 / 64)

typedef __attribute__((ext_vector_type(8))) short bf16x8;
typedef __attribute__((ext_vector_type(4))) float f32x4;

#define MFMA16(a, b, c) __builtin_amdgcn_mfma_f32_16x16x32_bf16((a), (b), (c), 0, 0, 0)

// async global -> LDS DMA, 16 B per lane, no VGPR destination.
__device__ __forceinline__ void gld_lds16(const float* g, float* l) {
    typedef const __attribute__((address_space(1))) void* gas_p;
    typedef __attribute__((address_space(3))) void* las_p;
    __builtin_amdgcn_global_load_lds((gas_p)g, (las_p)l, 16, 0, 0);
}

// fp32 -> bf16 truncation split: x = hi + lo with |x - hi - lo| <~ 2^-17 |x|.
__device__ __forceinline__ unsigned pack_hi(float a, float b) {
    return (__float_as_uint(a) >> 16) | (__float_as_uint(b) & 0xFFFF0000u);
}
__device__ __forceinline__ float hi_part(float a) {
    return __uint_as_float(__float_as_uint(a) & 0xFFFF0000u);
}
__device__ __forceinline__ void cvt_hilo(const float4 f0, const float4 f1,
                                         uint4& uh, uint4& ul) {
    uh.x = pack_hi(f0.x, f0.y);
    uh.y = pack_hi(f0.z, f0.w);
    uh.z = pack_hi(f1.x, f1.y);
    uh.w = pack_hi(f1.z, f1.w);
    const float l0 = f0.x - hi_part(f0.x), l1 = f0.y - hi_part(f0.y);
    const float l2 = f0.z - hi_part(f0.z), l3 = f0.w - hi_part(f0.w);
    const float l4 = f1.x - hi_part(f1.x), l5 = f1.y - hi_part(f1.y);
    const float l6 = f1.z - hi_part(f1.z), l7 = f1.w - hi_part(f1.w);
    ul.x = pack_hi(l0, l1);
    ul.y = pack_hi(l2, l3);
    ul.z = pack_hi(l4, l5);
    ul.w = pack_hi(l6, l7);
}

// Stage one wave's 16 vocab rows (19200 B) of tile `tile` into its half of dst.
// 19 global_load_lds dwordx4 wave-instrs; LDS dest = uniform base + lane*16.
__device__ __forceinline__ void stage16(const float* __restrict__ w_emb,
                                        int tile, int w, int lane, float* dst) {
    const float* gend = w_emb + (size_t)VV * EE - 4;
    const float* g = w_emb + ((size_t)tile * 64 + w * 16) * EE;
    float* d = dst + w * 4800;
#pragma unroll
    for (int i = 0; i < 19; ++i) {
        if (i < 18 || lane < 48) {             // 19200 B = 18.75 KB
            const int off = i * 256 + lane * 4;
            const float* src = g + off;
            if (src > gend) src = gend;        // tail-tile clamp, 16B-aligned
            gld_lds16(src, d + off);
        }
    }
}

// ---------------------------------------------------------------------------
// Kernel 1 (persistent, dbuf-DMA, B-in-VGPR):
// cent[v] = max_a ((cos(a_emb[a], w_emb[v]) > thres ? cos : 0) * w[a])
// Persistent grid 256 x 256 threads; each block loops ~3 tiles of 64 rows.
// LDS = two 76.8 KB A-buffers (1 block/CU). Each WAVE stages and consumes only
// its own 16 rows -> no barriers in the main loop; per-wave counted
// s_waitcnt vmcnt(19) keeps next tile's 19 DMA loads in flight across the
// whole current-tile compute (round 4's vmcnt(0)-before-compute serialized).
// B-fragments (a_emb hi/lo, 40 x bf16x8) live in 160 VGPRs, loop-invariant ->
// inner loop is 2 ds_read_b128 + cvt + 6 MFMA per k-step.
// Near-threshold cos (|cos-0.2| < 2e-4) re-checked in exact fp32 from LDS.
// ---------------------------------------------------------------------------
__global__ void __launch_bounds__(256, 1) cent_kernel(
    const float* __restrict__ w_emb,     // [V, E]
    const float* __restrict__ a_emb,     // [A, E]
    const float* __restrict__ a_weight,  // [A]
    float* __restrict__ cent)            // [V]
{
    __shared__ uint4 s_pool[9600];       // 153600 B: two 76800 B A-buffers
    __shared__ float s_scale[32];
    __shared__ float s_aw[32];

    const int t = threadIdx.x;
    const int l = t & 63;
    const int w = t >> 6;
    const int m = l & 15;        // vocab row within wave tile / aspect lane
    const int kg = l >> 4;       // k-chunk selector (8 elements each)

    // ---- aspect inv-norms + weights (8 lanes/aspect, threads 0..239) ----
    {
        const int a = t >> 3, j = t & 7;
        if (a < AA) {
            const float4* a4 = (const float4*)a_emb + a * 75;
            float n2a = 0.f;
            for (int c = j; c < 75; c += 8) {
                const float4 x = a4[c];
                n2a += x.x * x.x + x.y * x.y + x.z * x.z + x.w * x.w;
            }
            n2a += __shfl_xor(n2a, 1);
            n2a += __shfl_xor(n2a, 2);
            n2a += __shfl_xor(n2a, 4);
            if (j == 0) {
                s_scale[a] = 1.f / fmaxf(sqrtf(n2a), COS_EPS_F);
                s_aw[a] = a_weight[a];
            }
        }
        if (t == 30 || t == 31) { s_scale[t] = 0.f; s_aw[t] = 0.f; }  // pads
    }

    // ---- build B fragments (a_emb hi/lo) in pool[0..40960), then -> VGPRs ----
    {
        uint4* s_bfrag = s_pool;
        for (int ks = w; ks < 10; ks += 4) {
            const int kb = kg * 8 + 32 * ks;
#pragma unroll
            for (int tt = 0; tt < 2; ++tt) {
                const int col = tt * 16 + m;         // aspect index (pad >= 30)
                float4 f0 = {0.f, 0.f, 0.f, 0.f}, f1 = {0.f, 0.f, 0.f, 0.f};
                if (col < AA) {
                    const float* ap = a_emb + col * EE;
                    if (kb <= 296) f0 = *(const float4*)(ap + kb);
                    if (kb <= 292) f1 = *(const float4*)(ap + kb + 4);
                }
                uint4 uh, ul;
                cvt_hilo(f0, f1, uh, ul);
                s_bfrag[(ks * 4 + tt * 2 + 0) * 64 + l] = uh;
                s_bfrag[(ks * 4 + tt * 2 + 1) * 64 + l] = ul;
            }
        }
    }
    __syncthreads();

    bf16x8 bfr[40];                      // 160 VGPRs, loop-invariant
#pragma unroll
    for (int q = 0; q < 40; ++q)
        bfr[q] = __builtin_bit_cast(bf16x8, s_pool[q * 64 + l]);
    __syncthreads();                     // all reads done before DMA overwrites

    float* buf0 = (float*)s_pool;
    float* buf1 = buf0 + 19200;

    const float sc0 = s_scale[m], aw0 = s_aw[m];
    const float sc1 = s_scale[16 + m], aw1 = s_aw[16 + m];
    const bool col1ok = (16 + m) < AA;

    // ---- persistent tile loop, per-wave dbuf pipeline, barrier-free ----
    int cur = 0;
    int tile = blockIdx.x;
    stage16(w_emb, tile, w, l, buf0);

    for (; tile < NTILES; tile += CGRID) {
        const int nxt = tile + CGRID;
        float* bufc = cur ? buf1 : buf0;
        if (nxt < NTILES) {
            stage16(w_emb, nxt, w, l, cur ? buf0 : buf1);
            // wait tile's 19 loads only; next tile's 19 stay in flight
            asm volatile("s_waitcnt vmcnt(19)" ::: "memory");
        } else {
            asm volatile("s_waitcnt vmcnt(0)" ::: "memory");
        }

        const float* arow = bufc + w * 4800 + m * 300;
        f32x4 acc0 = {0.f, 0.f, 0.f, 0.f};
        f32x4 acc1 = {0.f, 0.f, 0.f, 0.f};
        float n2 = 0.f;
#pragma unroll
        for (int i = 0; i < 10; ++i) {
            const int kb = kg * 8 + 32 * i;
            float4 f0 = *(const float4*)(arow + kb);       // ds_read_b128
            float4 f1 = *(const float4*)(arow + kb + 4);
            if (i == 9) {                                  // zero-padded tail
                const float4 z = {0.f, 0.f, 0.f, 0.f};
                if (kg >= 2) f0 = z;                       // k >= 304
                if (kg >= 1) f1 = z;                       // k >= 300
            }
            n2 = fmaf(f0.x, f0.x, fmaf(f0.y, f0.y, fmaf(f0.z, f0.z, fmaf(f0.w, f0.w, n2))));
            n2 = fmaf(f1.x, f1.x, fmaf(f1.y, f1.y, fmaf(f1.z, f1.z, fmaf(f1.w, f1.w, n2))));
            uint4 uh, ul;
            cvt_hilo(f0, f1, uh, ul);
            const bf16x8 ah = __builtin_bit_cast(bf16x8, uh);
            const bf16x8 al = __builtin_bit_cast(bf16x8, ul);
            acc0 = MFMA16(ah, bfr[i * 4 + 0], acc0);
            acc1 = MFMA16(ah, bfr[i * 4 + 2], acc1);
            acc0 = MFMA16(ah, bfr[i * 4 + 1], acc0);
            acc1 = MFMA16(ah, bfr[i * 4 + 3], acc1);
            acc0 = MFMA16(al, bfr[i * 4 + 0], acc0);
            acc1 = MFMA16(al, bfr[i * 4 + 2], acc1);
        }

        // ---- epilogue ----
        n2 += __shfl_xor(n2, 16);
        n2 += __shfl_xor(n2, 32);
        // C/D layout: lane l holds D[rows kg*4+j][col m (+16 for acc1)]
        const int vtile = tile * 64 + w * 16;
        float mx[4];
#pragma unroll
        for (int j = 0; j < 4; ++j) {
            const int r = kg * 4 + j;             // row within wave tile
            const float n2r = __int_as_float(
                __builtin_amdgcn_ds_bpermute(r << 2, __float_as_int(n2)));
            const float inv_x = 1.f / fmaxf(sqrtf(n2r), COS_EPS_F);
            float c0 = acc0[j] * sc0 * inv_x;
            float c1 = acc1[j] * sc1 * inv_x;
            // exact fp32 recheck for near-threshold cos (reads LDS row copy)
            if (fabsf(c0 - WORD_THRES) < RECHECK_DELTA) {
                const float* wr = bufc + w * 4800 + r * 300;
                const float* ar = a_emb + m * EE;
                float d = 0.f;
                for (int k = 0; k < EE; ++k) d = fmaf(wr[k], ar[k], d);
                c0 = d * sc0 * inv_x;
            }
            if (col1ok && fabsf(c1 - WORD_THRES) < RECHECK_DELTA) {
                const float* wr = bufc + w * 4800 + r * 300;
                const float* ar = a_emb + (16 + m) * EE;
                float d = 0.f;
                for (int k = 0; k < EE; ++k) d = fmaf(wr[k], ar[k], d);
                c1 = d * sc1 * inv_x;
            }
            float mj = fmaxf((c0 > WORD_THRES) ? c0 * aw0 : 0.f,
                             (c1 > WORD_THRES) ? c1 * aw1 : 0.f);
            mj = fmaxf(mj, __shfl_xor(mj, 1));
            mj = fmaxf(mj, __shfl_xor(mj, 2));
            mj = fmaxf(mj, __shfl_xor(mj, 4));
            mj = fmaxf(mj, __shfl_xor(mj, 8));
            mx[j] = mj;
        }
        if (m == 0 && vtile < VV) {               // tail tile: waves 1-3 skip
            const float4 o = {mx[0], mx[1], mx[2], mx[3]};
            *(float4*)(cent + vtile + kg * 4) = o;
        }
        cur ^= 1;
    }
}

// ---------------------------------------------------------------------------
// Kernel 2: ONE WAVE per batch row (4 rows/block, 256 blocks). Lane owns 4
// contiguous positions -> int4 input load, 4 cent gathers, all reductions as
// one 6-level shuffle butterfly, coalesced float4 attention write. One barrier.
// Sparse z over the ~2 active positions per row.
// ---------------------------------------------------------------------------
__global__ void __launch_bounds__(256) row_kernel(
    const int* __restrict__ inputs,   // [B, L]
    const float* __restrict__ w_emb,  // [V, E]
    const float* __restrict__ cent,   // [V]
    float* __restrict__ out)          // enc_out [B,E] | a [B,L] | cs [B]
{
    const int w = threadIdx.x >> 6;
    const int lane = threadIdx.x & 63;
    const int b = blockIdx.x * 4 + w;           // wave-per-row

    __shared__ int s_id[4][LL];
    __shared__ float s_w[4][LL];
    __shared__ int s_n[4];

    if (lane == 0) s_n[w] = 0;

    const int4 id4 = *(const int4*)(inputs + b * LL + lane * 4);
    const float c0 = cent[id4.x];
    const float c1 = cent[id4.y];
    const float c2 = cent[id4.z];
    const float c3 = cent[id4.w];
    const float sc0 = (c0 > 0.f) ? c0 : NEG_INF_F;
    const float sc1 = (c1 > 0.f) ? c1 : NEG_INF_F;
    const float sc2 = (c2 > 0.f) ? c2 : NEG_INF_F;
    const float sc3 = (c3 > 0.f) ? c3 : NEG_INF_F;

    float s1 = c0 + c1 + c2 + c3;                             // sum cent
    float s2 = (id4.x != 0 ? 1.f : 0.f) + (id4.y != 0 ? 1.f : 0.f) +
               (id4.z != 0 ? 1.f : 0.f) + (id4.w != 0 ? 1.f : 0.f);
    float s3 = fmaxf(fmaxf(sc0, sc1), fmaxf(sc2, sc3));       // max score
#pragma unroll
    for (int o = 1; o < 64; o <<= 1) {
        s1 += __shfl_xor(s1, o);
        s2 += __shfl_xor(s2, o);
        s3 = fmaxf(s3, __shfl_xor(s3, o));
    }
    const float mx = s3;

    const float p0 = expf(sc0 - mx);
    const float p1 = expf(sc1 - mx);
    const float p2 = expf(sc2 - mx);
    const float p3 = expf(sc3 - mx);
    float s4 = p0 + p1 + p2 + p3;
#pragma unroll
    for (int o = 1; o < 64; o <<= 1) s4 += __shfl_xor(s4, o);

    const float rinv = 1.f / s4;
    const float4 av = {p0 * rinv, p1 * rinv, p2 * rinv, p3 * rinv};
    *(float4*)(out + BB * EE + b * LL + lane * 4) = av;       // attention

    const float cs = s1 / (s2 + 1e-5f);
    const float gate = (cs > 1e-4f) ? 1.f : 0.f;
    if (lane == 0) out[BB * EE + BB * LL + b] = cs;

    // per-wave active list (score > -1e8 <=> cent > 0)
    if (sc0 > -1e8f) { const int i = atomicAdd(&s_n[w], 1); s_id[w][i] = id4.x; s_w[w][i] = av.x; }
    if (sc1 > -1e8f) { const int i = atomicAdd(&s_n[w], 1); s_id[w][i] = id4.y; s_w[w][i] = av.y; }
    if (sc2 > -1e8f) { const int i = atomicAdd(&s_n[w], 1); s_id[w][i] = id4.z; s_w[w][i] = av.z; }
    if (sc3 > -1e8f) { const int i = atomicAdd(&s_n[w], 1); s_id[w][i] = id4.w; s_w[w][i] = av.w; }
    __syncthreads();                              // order LDS list vs reads
    const int n = s_n[w];

    // z over active entries; lane owns float4 col lane (+ col 64+lane if <11)
    float4 accA = {0.f, 0.f, 0.f, 0.f};
    float4 accB = {0.f, 0.f, 0.f, 0.f};
    for (int i = 0; i < n; ++i) {
        const float wgt = s_w[w][i];
        const float4* rp = (const float4*)(w_emb + (size_t)s_id[w][i] * EE);
        const float4 ra = rp[lane];
        accA.x += wgt * ra.x; accA.y += wgt * ra.y;
        accA.z += wgt * ra.z; accA.w += wgt * ra.w;
        if (lane < 11) {
            const float4 rb = rp[64 + lane];
            accB.x += wgt * rb.x; accB.y += wgt * rb.y;
            accB.z += wgt * rb.z; accB.w += wgt * rb.w;
        }
    }
    accA.x *= gate; accA.y *= gate; accA.z *= gate; accA.w *= gate;
    *(float4*)(out + b * EE + 4 * lane) = accA;
    if (lane < 11) {
        accB.x *= gate; accB.y *= gate; accB.z *= gate; accB.w *= gate;
        *(float4*)(out + b * EE + 256 + 4 * lane) = accB;
    }
}

// ---------------------------------------------------------------------------
extern "C" void kernel_launch(void* const* d_in, const int* in_sizes, int n_in,
                              void* d_out, int out_size, void* d_ws, size_t ws_size,
                              hipStream_t stream) {
    const int* inputs = (const int*)d_in[0];
    const float* w_emb = (const float*)d_in[1];
    const float* a_emb = (const float*)d_in[2];
    const float* a_weight = (const float*)d_in[3];
    float* out = (float*)d_out;
    float* cent = (float*)d_ws;  // 50000 floats = 200 KB scratch

    cent_kernel<<<CGRID, 256, 0, stream>>>(w_emb, a_emb, a_weight, cent);
    row_kernel<<<BB / 4, 256, 0, stream>>>(inputs, w_emb, cent, out);
}